// Round 9
// baseline (581.336 us; speedup 1.0000x reference)
//
#include <hip/hip_runtime.h>

// Problem constants (B, Cin, Cout, H, W) = (8, 256, 256, 128, 128)
#define BATCH 8
#define CIN   256
#define COUT  256
#define HH    128
#define WW    128
#define HW    (HH*WW)          // 16384

typedef __bf16 bf16x8 __attribute__((ext_vector_type(8)));
typedef float  f32x4  __attribute__((ext_vector_type(4)));
typedef unsigned short u16x8 __attribute__((ext_vector_type(8)));

__device__ __forceinline__ unsigned short f2bf(float f) {
    unsigned u = __float_as_uint(f);
    unsigned r = (u + 0x7fffu + ((u >> 16) & 1u)) >> 16;   // round-to-nearest-even
    return (unsigned short)r;
}

// ---------------------------------------------------------------------------
// Kernel 1: depthwise 3x3 conv (pad=1) -> bf16 Tt[b][p][c], SHUFFLE-FREE.
// R8 post-mortem: barrier-free conv still 103us, all pipes <25%. Common factor
// across every 87-103us variant: load->ds_bpermute(shfl)->FMA chains (96
// bpermutes + lgkm waits per thread). R9: halo via 2 extra aligned scalar
// loads per dy (same cache lines, L1 hits) + 2 edge cndmasks. Hot loop has
// ZERO DS ops. Weights in padded stride-12 LDS (float4-aligned broadcasts).
// hh unrolled so rows h,h+1 CSE across the two outputs. launch_bounds(,4)
// caps VGPR at 128 (4 blk/CU, 16 waves) -- R5 taught never to cap below need.
// Prep (W_b = pw + delta) folded in as 64 trailing blocks.
// XCD swizzle: XCD owns batch; hb fastest (halo rows L2-hot).
// ---------------------------------------------------------------------------
#define CONV_BLOCKS 2048   // 64 hb * 4 cb * 8 b
#define PREP_BLOCKS 64

__global__ __launch_bounds__(256, 4) void dwconv_prep_kernel(
    const float* __restrict__ x, const float* __restrict__ dw,
    const float* __restrict__ delta, const float* __restrict__ pw,
    unsigned short* __restrict__ Tt, unsigned short* __restrict__ Wb)
{
    const int tid = threadIdx.x;

    if ((int)blockIdx.x >= CONV_BLOCKS) {
        // ---- prep path: W_b[b][o][c] = bf16(pw[o][c] + delta[b][o][c]) ----
        const int t0 = (((int)blockIdx.x - CONV_BLOCKS) * 256 + tid) * 8;
        #pragma unroll
        for (int qq = 0; qq < 8; ++qq) {
            const int i = t0 + qq;                       // quad index
            float4 d = *(const float4*)(delta + (size_t)i * 4);
            const int j = (i * 4) & (COUT * CIN - 1);    // pw index (o*256+c)
            float4 p = *(const float4*)(pw + j);
            ushort4 r;
            r.x = f2bf(d.x + p.x);
            r.y = f2bf(d.y + p.y);
            r.z = f2bf(d.z + p.z);
            r.w = f2bf(d.w + p.w);
            *(ushort4*)(Wb + (size_t)i * 4) = r;
        }
        return;
    }

    __shared__ float kw[64 * 12];   // padded stride 12: float4-aligned (3KB)

    // bijective XCD swizzle: XCD (bid&7) owns batch (bid&7); hb fastest.
    const int L  = ((int)blockIdx.x & 7) * (CONV_BLOCKS / 8) + ((int)blockIdx.x >> 3);
    const int hb = L & 63;          // 2 h-rows: hb*2, hb*2+1
    const int cb = (L >> 6) & 3;    // 64-channel group
    const int b  = L >> 8;          // batch == XCD index

    // stage weights, padded 9 -> 12 floats per channel
    if (tid < 64) {
        const float* s = dw + (size_t)(cb * 64 + tid) * 9;
        float* d = kw + tid * 12;
        #pragma unroll
        for (int j = 0; j < 9; ++j) d[j] = s[j];
    }
    __syncthreads();   // the ONLY barrier

    const int wq = tid & 31;     // w-quad: covers w0..w0+3
    const int cs = tid >> 5;     // 0..7: channels cs*8 .. cs*8+7 (consecutive)
    const int w0 = wq * 4;
    const int lo_off = (wq == 0)  ? 0        : (w0 - 1);   // addr of xm1 (clamped)
    const int hi_off = (wq == 31) ? (WW - 1) : (w0 + 4);   // addr of x4  (clamped)
    const bool e0  = (wq == 0);
    const bool e31 = (wq == 31);

    #pragma unroll
    for (int hh = 0; hh < 2; ++hh) {
        const int h = hb * 2 + hh;
        u16x8 v0, v1, v2, v3;    // bf16 outputs for w0..w0+3; elem index = ci
        #pragma unroll
        for (int ci = 0; ci < 8; ++ci) {
            const int c  = cs * 8 + ci;                  // local channel 0..63
            const float* xp = x + ((size_t)(b * CIN + cb * 64 + c)) * HW;
            const float4 ka = *(const float4*)(kw + c * 12);      // k0..k3
            const float4 kb = *(const float4*)(kw + c * 12 + 4);  // k4..k7
            const float  k8 = kw[c * 12 + 8];
            float a0 = 0.f, a1 = 0.f, a2 = 0.f, a3 = 0.f;
            #pragma unroll
            for (int dy = 0; dy < 3; ++dy) {
                const int r = h + dy - 1;
                float4 v = {0.f, 0.f, 0.f, 0.f};
                float xm1 = 0.f, x4 = 0.f;
                if (r >= 0 && r < HH) {
                    const float* rowp = xp + r * WW;
                    v   = *(const float4*)(rowp + w0);   // x0..x3 (16B aligned)
                    xm1 = rowp[lo_off];                  // x[-1] (clamped addr)
                    x4  = rowp[hi_off];                  // x[+4] (clamped addr)
                    if (e0)  xm1 = 0.f;                  // w=-1 pad
                    if (e31) x4  = 0.f;                  // w=128 pad
                }
                const float k0 = (dy == 0) ? ka.x : (dy == 1) ? ka.w : kb.z;
                const float k1 = (dy == 0) ? ka.y : (dy == 1) ? kb.x : kb.w;
                const float k2 = (dy == 0) ? ka.z : (dy == 1) ? kb.y : k8;
                a0 += k0 * xm1 + k1 * v.x + k2 * v.y;
                a1 += k0 * v.x + k1 * v.y + k2 * v.z;
                a2 += k0 * v.y + k1 * v.z + k2 * v.w;
                a3 += k0 * v.z + k1 * v.w + k2 * x4;
            }
            v0[ci] = f2bf(a0); v1[ci] = f2bf(a1);
            v2[ci] = f2bf(a2); v3[ci] = f2bf(a3);
        }
        // direct 16B stores: Tt[b][p = h*128 + w][cb*64 + cs*8 .. +7]
        unsigned short* tp = Tt + ((size_t)b * HW + (size_t)h * WW + w0) * CIN
                                + cb * 64 + cs * 8;
        *(u16x8*)(tp)            = v0;
        *(u16x8*)(tp + CIN)      = v1;
        *(u16x8*)(tp + 2 * CIN)  = v2;
        *(u16x8*)(tp + 3 * CIN)  = v3;
    }
}

// ---------------------------------------------------------------------------
// Kernel 2: per-batch GEMM  out[b][o][p] = sum_c Wb[b][o][c] * Tt[b][p][c]
// UNCHANGED from R1/R3/R8 (passed on HW 3x): BK=64, XOR-swizzled LDS via
// pre-swizzled global source, XCD swizzle batch==XCD.
// ---------------------------------------------------------------------------
__global__ __launch_bounds__(256) void gemm_kernel(
    const unsigned short* __restrict__ Wb,
    const unsigned short* __restrict__ Tt,
    float* __restrict__ out)
{
    __shared__ unsigned short lA[128 * 64];   // [row][slot ^ (row&7)], 16B slots
    __shared__ unsigned short lB[128 * 64];

    const int L  = ((int)blockIdx.x & 7) * 256 + ((int)blockIdx.x >> 3);
    const int mt = L & 1;
    const int nt = (L >> 1) & 127;
    const int b  = L >> 8;
    const int tid = threadIdx.x;

    const unsigned short* Ab = Wb + ((size_t)b * COUT + mt * 128) * CIN;   // [128][256]
    const unsigned short* Bb = Tt + ((size_t)b * HW + nt * 128) * CIN;     // [128][256]

    const int lane = tid & 63;
    const int wv   = tid >> 6;
    const int wm   = (wv & 1) * 64;
    const int wn   = (wv >> 1) * 64;
    const int q    = lane >> 4;     // quad 0..3
    const int rrow = lane & 15;

    f32x4 acc[4][4] = {};

    for (int k0 = 0; k0 < CIN; k0 += 64) {
        #pragma unroll
        for (int r = 0; r < 4; ++r) {
            const int i     = r * 256 + tid;    // 16B chunk id, 0..1023
            const int row   = i >> 3;           // 0..127
            const int pslot = i & 7;            // physical 16B slot in row
            const int lslot = pslot ^ (row & 7);// logical slot fetched here
            const unsigned short* ga = Ab + (size_t)row * CIN + k0 + lslot * 8;
            const unsigned short* gb = Bb + (size_t)row * CIN + k0 + lslot * 8;
            __builtin_amdgcn_global_load_lds(
                (const __attribute__((address_space(1))) void*)ga,
                (__attribute__((address_space(3))) void*)(lA + (size_t)i * 8),
                16, 0, 0);
            __builtin_amdgcn_global_load_lds(
                (const __attribute__((address_space(1))) void*)gb,
                (__attribute__((address_space(3))) void*)(lB + (size_t)i * 8),
                16, 0, 0);
        }
        __syncthreads();

        #pragma unroll
        for (int kk = 0; kk < 2; ++kk) {
            bf16x8 af[4], bfv[4];
            const int slot = (kk * 4 + q) ^ (rrow & 7);   // row&7 == rrow&7 here
            #pragma unroll
            for (int i = 0; i < 4; ++i) {
                af[i]  = *(const bf16x8*)&lA[(wm + i * 16 + rrow) * 64 + slot * 8];
                bfv[i] = *(const bf16x8*)&lB[(wn + i * 16 + rrow) * 64 + slot * 8];
            }
            #pragma unroll
            for (int i = 0; i < 4; ++i)
                #pragma unroll
                for (int j = 0; j < 4; ++j)
                    acc[i][j] = __builtin_amdgcn_mfma_f32_16x16x32_bf16(af[i], bfv[j], acc[i][j], 0, 0, 0);
        }
        __syncthreads();
    }

    // epilogue: C/D map col=lane&15, row=quad*4+reg
    float* outp = out + ((size_t)b * COUT + mt * 128 + wm) * HW + (size_t)nt * 128 + wn;
    #pragma unroll
    for (int i = 0; i < 4; ++i)
        #pragma unroll
        for (int j = 0; j < 4; ++j)
            #pragma unroll
            for (int rr = 0; rr < 4; ++rr)
                outp[(size_t)(i * 16 + q * 4 + rr) * HW + j * 16 + rrow] = acc[i][j][rr];
}

// ---------------------------------------------------------------------------
extern "C" void kernel_launch(void* const* d_in, const int* in_sizes, int n_in,
                              void* d_out, int out_size, void* d_ws, size_t ws_size,
                              hipStream_t stream)
{
    const float* x     = (const float*)d_in[0];   // (8,256,128,128)
    const float* delta = (const float*)d_in[1];   // (8,256,256,1,1)
    const float* dw    = (const float*)d_in[2];   // (256,1,3,3)
    const float* pw    = (const float*)d_in[3];   // (256,256,1,1)
    float* out = (float*)d_out;                   // (8,256,128,128)

    // workspace: Tt bf16 [8][16384][256] = 64 MiB, then Wb bf16 [8][256][256] = 1 MiB
    unsigned short* Tt = (unsigned short*)d_ws;
    unsigned short* Wb = (unsigned short*)((char*)d_ws + (size_t)BATCH * HW * CIN * 2);

    dwconv_prep_kernel<<<dim3(CONV_BLOCKS + PREP_BLOCKS), dim3(256), 0, stream>>>(
        x, dw, delta, pw, Tt, Wb);
    gemm_kernel<<<dim3(2048), dim3(256), 0, stream>>>(Wb, Tt, out);
}